// Round 18
// baseline (40.757 us; speedup 1.0000x reference)
//
#include <hip/hip_runtime.h>
#include <math.h>

// B=2, C=64, H=W=128, N=9, KS=3, PAD=1.
// Round 18 = r17 (32-px blocks, 4 blocks/CU, sample-parity ph2) + depth-1
// software pipeline in phase 2: next iteration's w4/i4 preloaded in named regs
// while current iteration computes (loop stays ROLLED -- r12/r15 spill lesson;
// manual peel adds only ~16 VGPR). Hides the ~300cy per-iteration LDS/L2
// latency bubble the rolled loop exposed.
// Offset conv stays split-bf16 3-term MFMA (fp32-grade offsets; the reference
// depth bilinear is discontinuous at coord 127 and amplifies offset error).
// k map (same for A and B packs; HW k-permutation cancels):
//   k = s*32 + h*8 + e;  t/n = s>>1;  c = (s&1)*32 + h*8 + e.
// C/D: col = lane&15 (pixel), row = h*4+reg. Verified r3-r17.

typedef __attribute__((ext_vector_type(8))) short bf16x8;
typedef __attribute__((ext_vector_type(4))) short s16x4;
typedef __attribute__((ext_vector_type(4))) float f32x4;

#define MFMA16(a, b, c) __builtin_amdgcn_mfma_f32_16x16x32_bf16((a), (b), (c), 0, 0, 0)

__device__ __forceinline__ float bf2f(short v) {
    return __uint_as_float(((unsigned)(unsigned short)v) << 16);
}
__device__ __forceinline__ short f2bf(float f) {
    unsigned u = __float_as_uint(f);
    u = u + 0x7fffu + ((u >> 16) & 1u);
    return (short)(u >> 16);
}

// ---------------- prep: LDS-transpose x -> xT/xTlo; pack wK, wPh, wPl ----------------
__global__ __launch_bounds__(256) void k_prep(const float* __restrict__ x,
                                              const float* __restrict__ w_conv,
                                              const float* __restrict__ w_p,
                                              short* __restrict__ xT,
                                              short* __restrict__ xTlo,
                                              short* __restrict__ wK,
                                              short* __restrict__ wPh,
                                              short* __restrict__ wPl) {
    __shared__ short sH[128][72];
    __shared__ short sL[128][72];
    int bid = blockIdx.x;
    int tid = threadIdx.x;
    if (bid < 256) {
        int p = tid & 127;
        int halfc = tid >> 7;
        int pix0 = bid << 7;
        int b = pix0 >> 14;
        const float* xb = x + (size_t)b * 64 * 16384 + (pix0 & 16383);
#pragma unroll
        for (int cc = 0; cc < 8; ++cc) {
            int c0 = cc * 8 + halfc * 4;
            union { short s[4]; s16x4 v; } hi, lo;
#pragma unroll
            for (int e = 0; e < 4; ++e) {
                float v = xb[(c0 + e) * 16384 + p];
                short hb = f2bf(v);
                hi.s[e] = hb;
                lo.s[e] = f2bf(v - bf2f(hb));
            }
            *reinterpret_cast<s16x4*>(&sH[p][c0]) = hi.v;
            *reinterpret_cast<s16x4*>(&sL[p][c0]) = lo.v;
        }
        __syncthreads();
        short* xTo = xT   + ((size_t)pix0 << 6);
        short* xLo = xTlo + ((size_t)pix0 << 6);
#pragma unroll
        for (int r = 0; r < 4; ++r) {
            int u = (r << 8) + tid;
            int pp = u >> 3, ch8 = u & 7;
            *reinterpret_cast<bf16x8*>(xTo + pp * 64 + ch8 * 8) =
                *reinterpret_cast<const bf16x8*>(&sH[pp][ch8 * 8]);
            *reinterpret_cast<bf16x8*>(xLo + pp * 64 + ch8 * 8) =
                *reinterpret_cast<const bf16x8*>(&sL[pp][ch8 * 8]);
        }
    } else {
        int idx = (bid - 256) * 256 + tid;
        if (idx >= 55296) return;
        if (idx < 36864) {
            int e = idx & 7, o = (idx >> 3) & 63, h = (idx >> 9) & 3, s = idx >> 11;
            int k = s * 32 + h * 8 + e;
            int n = k >> 6, c = k & 63;
            wK[idx] = f2bf(w_conv[o * 576 + c * 9 + n]);
        } else {
            int j = idx - 36864;
            int e = j & 7, m = (j >> 3) & 31, h = (j >> 8) & 3, s = j >> 10;
            int k = s * 32 + h * 8 + e;
            int t = k >> 6, c = k & 63;
            float v = (m < 18) ? w_p[m * 576 + c * 9 + t] : 0.f;
            short hb = f2bf(v);
            wPh[j] = hb;
            wPl[j] = f2bf(v - bf2f(hb));
        }
    }
}

// ---------------- fused: 256 thr = 4 waves on 32 px; 4 blocks/CU ----------------
__global__ __launch_bounds__(256, 4) void k_fused(const short* __restrict__ xT,
                                                  const short* __restrict__ xTlo,
                                                  const short* __restrict__ wPh,
                                                  const short* __restrict__ wPl,
                                                  const short* __restrict__ wK,
                                                  const float* __restrict__ depth,
                                                  const float* __restrict__ b_p,
                                                  float* __restrict__ out) {
    // layout (bytes):
    //   win    [0,     23680)  x hi window: 185 px (5r x 37c) x 128B, XOR-swizzled
    //   dwin   [23680, 24420)  float[185]
    //   part1  [24448, 29568)  float[2][2][16][20]
    //   pw4    [29568, 34176)  float4[288]  (bilinear weights x m)
    //   pi4    [34176, 38784)  int4[288]    (corner indices; <0 => global fallback)
    //   accred overlays win [0, 10240): float[2*64][20] stride-20 (conflict-free)
    __shared__ __align__(16) char smem[38784];
    short* win    = (short*)smem;
    float* dwin   = (float*)(smem + 23680);
    float* part1  = (float*)(smem + 24448);
    float* pw4    = (float*)(smem + 29568);
    int*   pi4    = (int*)(smem + 34176);
    float* accred = (float*)smem;

    int tid = threadIdx.x;
    int lane = tid & 63;
    int wv = tid >> 6;                      // 0..3
    int l15 = lane & 15, h = lane >> 4;
    int ps = wv & 1;                        // pixel subtile (16 px)
    int kh = wv >> 1;                       // channel-half (ph1) / sample parity (ph2)
    int p0 = ps << 4;
    // XCD band swizzle (bijective: 1024 = 8*128)
    int bid = blockIdx.x;
    int swz = (bid & 7) * 128 + (bid >> 3);
    int pb = swz << 5;                      // 32-px tile
    int b = pb >> 14, i = (pb & 16383) >> 7, j0 = pb & 127;
    const short* xTb  = xT   + ((size_t)b << 20);
    const short* xTlb = xTlo + ((size_t)b << 20);
    const float* db = depth + (b << 14);

    // ---- stage: x hi window (5r x 37c) + depth window; coalesced ----
    for (int u = tid; u < 1480; u += 256) {
        int c8 = u & 7, px = u >> 3;
        int wr = px / 37, wc = px % 37;
        int r = i - 2 + wr, c = j0 - 2 + wc;
        bf16x8 v = {0, 0, 0, 0, 0, 0, 0, 0};
        if ((unsigned)r < 128u && (unsigned)c < 128u)
            v = *reinterpret_cast<const bf16x8*>(xTb + ((size_t)(r * 128 + c) << 6) + c8 * 8);
        *reinterpret_cast<bf16x8*>((char*)win + px * 128 + ((c8 ^ (px & 7)) << 4)) = v;
    }
    if (tid < 185) {
        int wr = tid / 37, wc = tid % 37;
        int r = i - 2 + wr, c = j0 - 2 + wc;
        dwin[tid] = ((unsigned)r < 128u && (unsigned)c < 128u) ? db[r * 128 + c] : 0.f;
    }
    __syncthreads();

    // ---- phase 1: offset conv; wave (ps,kh): 9 taps, channel half kh ----
    f32x4 acc0 = {0.f, 0.f, 0.f, 0.f}, acc1 = {0.f, 0.f, 0.f, 0.f};
    int c8p = kh * 4 + h;
#pragma unroll
    for (int t = 0; t < 9; ++t) {
        int s_ = t * 2 + kh;
        int wp = (t / 3 + 1) * 37 + (p0 + l15 + t % 3 + 1);
        bf16x8 bh = *reinterpret_cast<const bf16x8*>(
            (char*)win + wp * 128 + ((c8p ^ (wp & 7)) << 4));
        int si = i + t / 3 - 1;
        int sj = j0 + p0 + l15 + t % 3 - 1;
        bf16x8 bl = {0, 0, 0, 0, 0, 0, 0, 0};
        if ((unsigned)si < 128u && (unsigned)sj < 128u)
            bl = *reinterpret_cast<const bf16x8*>(
                xTlb + ((size_t)(si * 128 + sj) << 6) + c8p * 8);
        const short* wh_ = wPh + (size_t)((s_ * 4 + h) * 32 + l15) * 8;
        const short* wl_ = wPl + (size_t)((s_ * 4 + h) * 32 + l15) * 8;
        bf16x8 ah0 = *reinterpret_cast<const bf16x8*>(wh_);
        bf16x8 ah1 = *reinterpret_cast<const bf16x8*>(wh_ + 128);
        bf16x8 al0 = *reinterpret_cast<const bf16x8*>(wl_);
        bf16x8 al1 = *reinterpret_cast<const bf16x8*>(wl_ + 128);
        acc0 = MFMA16(ah0, bh, acc0);
        acc1 = MFMA16(ah1, bh, acc1);
        acc0 = MFMA16(ah0, bl, acc0);
        acc1 = MFMA16(ah1, bl, acc1);
        acc0 = MFMA16(al0, bh, acc0);
        acc1 = MFMA16(al1, bh, acc1);
    }
    {
        float* pp = part1 + ((ps * 2 + kh) * 16 + l15) * 20;
#pragma unroll
        for (int r = 0; r < 4; ++r) {
            pp[h * 4 + r] = acc0[r];
            int o1 = 16 + h * 4 + r;
            if (o1 < 18) pp[o1] = acc1[r];
        }
    }
    __syncthreads();

    // ---- epilogue: unit u = (p, n); offs inlined; depth bilinear -> pw4/pi4 ----
#pragma clang loop unroll(disable)
    for (int u = tid; u < 288; u += 256) {
        int p = u / 9, n = u % 9;
        int pps = p >> 4, pl = p & 15;
        const float* pa  = part1 + ((pps * 2) * 16 + pl) * 20;
        const float* pbm = part1 + ((pps * 2 + 1) * 16 + pl) * 20;
        float offx = pa[n] + pbm[n] + b_p[n];
        float offy = pa[9 + n] + pbm[9 + n] + b_p[9 + n];
        float gx = (float)(n / 3 - 1 + i + 1);
        float gy = (float)(n % 3 - 1 + j0 + p + 1);
        float dctr = dwin[2 * 37 + p + 2];
        float p1x = offx + gx, p1y = offy + gy;
        float fx = floorf(p1x), fy = floorf(p1y);
        float qltx = fminf(fmaxf(fx, 0.f), 127.f);
        float qlty = fminf(fmaxf(fy, 0.f), 127.f);
        float qrbx = fminf(fmaxf(fx + 1.f, 0.f), 127.f);
        float qrby = fminf(fmaxf(fy + 1.f, 0.f), 127.f);
        float pxc = fminf(fmaxf(p1x, 0.f), 127.f);
        float pyc = fminf(fmaxf(p1y, 0.f), 127.f);
        float glt = (1.f + (qltx - pxc)) * (1.f + (qlty - pyc));
        float grb = (1.f - (qrbx - pxc)) * (1.f - (qrby - pyc));
        float glb = (1.f + (qltx - pxc)) * (1.f - (qrby - pyc));
        float grt = (1.f - (qrbx - pxc)) * (1.f + (qlty - pyc));
        int ilx = (int)qltx, ily = (int)qlty, irx = (int)qrbx, iry = (int)qrby;
        auto dv = [&](int qx, int qy) -> float {
            if (qx < 1 || qx > 128 || qy < 1 || qy > 128) return 0.f;
            int r = qx - 1, c = qy - 1;
            int wr = r - (i - 2), wc = c - (j0 - 2);
            if ((unsigned)wr < 5u && (unsigned)wc < 37u) return dwin[wr * 37 + wc];
            return db[r * 128 + c];   // rare fallback
        };
        float dof = glt * dv(ilx, ily) + grb * dv(irx, iry) + glb * dv(ilx, iry) + grt * dv(irx, ily);
        float dd = fabsf(dctr - dof);
        float dwn = expf(-4.f * dd) + 0.25f;
        float mn = expf(-dd);
        float px = offx * dwn + gx;
        float py = offy * dwn + gy;
        float fx2 = floorf(px), fy2 = floorf(py);
        float xltx = fminf(fmaxf(fx2, 0.f), 129.f);
        float xlty = fminf(fmaxf(fy2, 0.f), 129.f);
        float xrbx = fminf(fmaxf(fx2 + 1.f, 0.f), 129.f);
        float xrby = fminf(fmaxf(fy2 + 1.f, 0.f), 129.f);
        float xpxc = fminf(fmaxf(px, 0.f), 129.f);
        float xpyc = fminf(fmaxf(py, 0.f), 129.f);
        float wlt = (1.f + (xltx - xpxc)) * (1.f + (xlty - xpyc));
        float wrb = (1.f - (xrbx - xpxc)) * (1.f - (xrby - xpyc));
        float wlb = (1.f + (xltx - xpxc)) * (1.f - (xrby - xpyc));
        float wrt = (1.f - (xrbx - xpxc)) * (1.f + (xlty - xpyc));
        int jlx = (int)xltx, jly = (int)xlty, jrx = (int)xrbx, jry = (int)xrby;
        float w4o[4];
        int i4o[4];
        auto mk = [&](int qx, int qy, float gw, int slot) {
            bool ok = (qx >= 1 && qx <= 128 && qy >= 1 && qy <= 128);
            w4o[slot] = ok ? gw * mn : 0.f;
            int idx = 0;   // weight 0 kills the (valid) window[0] read
            if (ok) {
                int r = qx - 1, c = qy - 1;
                int wr = r - (i - 2), wc = c - (j0 - 2);
                idx = ((unsigned)wr < 5u && (unsigned)wc < 37u) ? (wr * 37 + wc)
                                                                : (-1 - (r * 128 + c));
            }
            i4o[slot] = idx;
        };
        mk(jlx, jly, wlt, 0);
        mk(jrx, jry, wrb, 1);
        mk(jlx, jry, wlb, 2);
        mk(jrx, jly, wrt, 3);
        *reinterpret_cast<float4*>(pw4 + u * 4) = make_float4(w4o[0], w4o[1], w4o[2], w4o[3]);
        *reinterpret_cast<int4*>(pi4 + u * 4) = make_int4(i4o[0], i4o[1], i4o[2], i4o[3]);
    }

    // ---- prefetch first phase-2 iteration's wK frags (static addrs) ----
    const short* wkf0 = wK + (size_t)((kh * 8 + h) * 64 + l15) * 8;
    const short* wkf1 = wkf0 + 2048;
    bf16x8 f00 = *reinterpret_cast<const bf16x8*>(wkf0);
    bf16x8 f01 = *reinterpret_cast<const bf16x8*>(wkf0 + 128);
    bf16x8 f02 = *reinterpret_cast<const bf16x8*>(wkf0 + 256);
    bf16x8 f03 = *reinterpret_cast<const bf16x8*>(wkf0 + 384);
    bf16x8 f10 = *reinterpret_cast<const bf16x8*>(wkf1);
    bf16x8 f11 = *reinterpret_cast<const bf16x8*>(wkf1 + 128);
    bf16x8 f12 = *reinterpret_cast<const bf16x8*>(wkf1 + 256);
    bf16x8 f13 = *reinterpret_cast<const bf16x8*>(wkf1 + 384);
    __syncthreads();

    // ---- phase 2: raw-tap MFMA; wave (ps,kh): samples n%2==kh ----
    // depth-1 pipeline on (w4,i4): next iteration's records preloaded in regs.
    f32x4 A0 = {0.f, 0.f, 0.f, 0.f}, A1 = {0.f, 0.f, 0.f, 0.f};
    f32x4 A2 = {0.f, 0.f, 0.f, 0.f}, A3 = {0.f, 0.f, 0.f, 0.f};
    int ubase = (p0 + l15) * 9;
    auto ph2_body = [&](float4 w4, int4 i4,
                        bf16x8 a00, bf16x8 a01, bf16x8 a02, bf16x8 a03,
                        bf16x8 a10, bf16x8 a11, bf16x8 a12, bf16x8 a13) {
        const int* ip = &i4.x;
        const float* wp = &w4.x;
#pragma unroll
        for (int t = 0; t < 4; ++t) {
            int idx = ip[t];
            float w = wp[t];
            bf16x8 th0, th1;
            if (idx >= 0) {
                const char* base = (char*)win + idx * 128;
                th0 = *reinterpret_cast<const bf16x8*>(base + ((h ^ (idx & 7)) << 4));
                th1 = *reinterpret_cast<const bf16x8*>(base + (((4 + h) ^ (idx & 7)) << 4));
            } else {
                int gp = -1 - idx;   // rare global fallback
                const short* gb = xTb + ((size_t)gp << 6) + h * 8;
                th0 = *reinterpret_cast<const bf16x8*>(gb);
                th1 = *reinterpret_cast<const bf16x8*>(gb + 32);
            }
            f32x4 Z = {0.f, 0.f, 0.f, 0.f};
            f32x4 D0 = MFMA16(a00, th0, Z);
            f32x4 D1 = MFMA16(a01, th0, Z);
            f32x4 D2 = MFMA16(a02, th0, Z);
            f32x4 D3 = MFMA16(a03, th0, Z);
            D0 = MFMA16(a10, th1, D0);
            D1 = MFMA16(a11, th1, D1);
            D2 = MFMA16(a12, th1, D2);
            D3 = MFMA16(a13, th1, D3);
            A0 += w * D0;
            A1 += w * D1;
            A2 += w * D2;
            A3 += w * D3;
        }
    };
    // peel n = kh with prefetched wK frags; preload (w4,i4) for n = kh+2 first
    float4 w4c = {0.f, 0.f, 0.f, 0.f};
    int4 i4c = {0, 0, 0, 0};
    if (kh + 2 < 9) {
        w4c = *reinterpret_cast<const float4*>(pw4 + (ubase + kh + 2) * 4);
        i4c = *reinterpret_cast<const int4*>(pi4 + (ubase + kh + 2) * 4);
    }
    {
        float4 w40 = *reinterpret_cast<const float4*>(pw4 + (ubase + kh) * 4);
        int4 i40 = *reinterpret_cast<const int4*>(pi4 + (ubase + kh) * 4);
        ph2_body(w40, i40, f00, f01, f02, f03, f10, f11, f12, f13);
    }
#pragma clang loop unroll(disable)
    for (int n = kh + 2; n < 9; n += 2) {
        // preload next iteration's (w4,i4) before computing this one
        float4 w4n = {0.f, 0.f, 0.f, 0.f};
        int4 i4n = {0, 0, 0, 0};
        int nn = n + 2;
        if (nn < 9) {
            w4n = *reinterpret_cast<const float4*>(pw4 + (ubase + nn) * 4);
            i4n = *reinterpret_cast<const int4*>(pi4 + (ubase + nn) * 4);
        }
        const short* wk0 = wK + (size_t)((n * 8 + h) * 64 + l15) * 8;
        const short* wk1 = wk0 + 2048;
        ph2_body(w4c, i4c,
                 *reinterpret_cast<const bf16x8*>(wk0),
                 *reinterpret_cast<const bf16x8*>(wk0 + 128),
                 *reinterpret_cast<const bf16x8*>(wk0 + 256),
                 *reinterpret_cast<const bf16x8*>(wk0 + 384),
                 *reinterpret_cast<const bf16x8*>(wk1),
                 *reinterpret_cast<const bf16x8*>(wk1 + 128),
                 *reinterpret_cast<const bf16x8*>(wk1 + 256),
                 *reinterpret_cast<const bf16x8*>(wk1 + 384));
        w4c = w4n;
        i4c = i4n;
    }
    __syncthreads();   // win dead -> accred overlay valid
    if (kh == 1) {
        float* ar = accred + (ps * 64 + lane) * 20;
        *reinterpret_cast<f32x4*>(ar)      = A0;
        *reinterpret_cast<f32x4*>(ar + 4)  = A1;
        *reinterpret_cast<f32x4*>(ar + 8)  = A2;
        *reinterpret_cast<f32x4*>(ar + 12) = A3;
    }
    __syncthreads();
    if (kh == 0) {
        const float* ar = accred + (ps * 64 + lane) * 20;
        int col = j0 + p0 + l15;
        size_t orow = ((size_t)b << 20) + ((size_t)i << 7) + col;   // o = 0 base
#pragma unroll
        for (int r = 0; r < 4; ++r) {
            out[orow + ((size_t)(h * 4 + r) << 14)]      = A0[r] + ar[r];
            out[orow + ((size_t)(16 + h * 4 + r) << 14)] = A1[r] + ar[4 + r];
            out[orow + ((size_t)(32 + h * 4 + r) << 14)] = A2[r] + ar[8 + r];
            out[orow + ((size_t)(48 + h * 4 + r) << 14)] = A3[r] + ar[12 + r];
        }
    }
}

extern "C" void kernel_launch(void* const* d_in, const int* in_sizes, int n_in,
                              void* d_out, int out_size, void* d_ws, size_t ws_size,
                              hipStream_t stream) {
    (void)in_sizes; (void)n_in; (void)out_size; (void)ws_size;
    const float* x      = (const float*)d_in[0];
    const float* depth  = (const float*)d_in[1];
    const float* w_p    = (const float*)d_in[2];
    const float* b_p    = (const float*)d_in[3];
    const float* w_conv = (const float*)d_in[4];
    float* out = (float*)d_out;

    char* wsb = (char*)d_ws;
    short* xT   = (short*)wsb;                     // 4,194,304 B
    short* xTlo = (short*)(wsb + 4194304);         // 4,194,304 B
    short* wK   = (short*)(wsb + 8388608);         //    73,728 B
    short* wPh  = (short*)(wsb + 8462336);         //    36,864 B
    short* wPl  = (short*)(wsb + 8499200);         //    36,864 B  (total ~8.54 MB)

    hipLaunchKernelGGL(k_prep,  dim3(472),  dim3(256), 0, stream,
                       x, w_conv, w_p, xT, xTlo, wK, wPh, wPl);
    hipLaunchKernelGGL(k_fused, dim3(1024), dim3(256), 0, stream,
                       xT, xTlo, wPh, wPl, wK, depth, b_p, out);
}

// Round 19
// 35.179 us; speedup vs baseline: 1.1586x; 1.1586x over previous
//
#include <hip/hip_runtime.h>
#include <math.h>

// B=2, C=64, H=W=128, N=9, KS=3, PAD=1.
// Round 19 = EXACT revert to r17 (best: 35.2us). r18's manual depth-1 pipeline
// regressed to 40.8 (third failed scheduling intervention: r6 ILP macros null,
// r12/r15 unrolls spilled, r18 peeled regs -16%) -- hipcc schedules the rolled
// loop better than hand pipelines. Structure: 1024 blocks x 256 thr (4 waves)
// on 32-px tiles, 4 blocks/CU, sample-parity phase-2 split + accred reduce.
// Offset conv = split-bf16 3-term MFMA (fp32-grade offsets; the reference
// depth bilinear is discontinuous at coord 127 and amplifies offset error).
// k map (same for A and B packs; HW k-permutation cancels):
//   k = s*32 + h*8 + e;  t/n = s>>1;  c = (s&1)*32 + h*8 + e.
// C/D: col = lane&15 (pixel), row = h*4+reg. Verified r3-r18.

typedef __attribute__((ext_vector_type(8))) short bf16x8;
typedef __attribute__((ext_vector_type(4))) short s16x4;
typedef __attribute__((ext_vector_type(4))) float f32x4;

#define MFMA16(a, b, c) __builtin_amdgcn_mfma_f32_16x16x32_bf16((a), (b), (c), 0, 0, 0)

__device__ __forceinline__ float bf2f(short v) {
    return __uint_as_float(((unsigned)(unsigned short)v) << 16);
}
__device__ __forceinline__ short f2bf(float f) {
    unsigned u = __float_as_uint(f);
    u = u + 0x7fffu + ((u >> 16) & 1u);
    return (short)(u >> 16);
}

// ---------------- prep: LDS-transpose x -> xT/xTlo; pack wK, wPh, wPl ----------------
__global__ __launch_bounds__(256) void k_prep(const float* __restrict__ x,
                                              const float* __restrict__ w_conv,
                                              const float* __restrict__ w_p,
                                              short* __restrict__ xT,
                                              short* __restrict__ xTlo,
                                              short* __restrict__ wK,
                                              short* __restrict__ wPh,
                                              short* __restrict__ wPl) {
    __shared__ short sH[128][72];
    __shared__ short sL[128][72];
    int bid = blockIdx.x;
    int tid = threadIdx.x;
    if (bid < 256) {
        int p = tid & 127;
        int halfc = tid >> 7;
        int pix0 = bid << 7;
        int b = pix0 >> 14;
        const float* xb = x + (size_t)b * 64 * 16384 + (pix0 & 16383);
#pragma unroll
        for (int cc = 0; cc < 8; ++cc) {
            int c0 = cc * 8 + halfc * 4;
            union { short s[4]; s16x4 v; } hi, lo;
#pragma unroll
            for (int e = 0; e < 4; ++e) {
                float v = xb[(c0 + e) * 16384 + p];
                short hb = f2bf(v);
                hi.s[e] = hb;
                lo.s[e] = f2bf(v - bf2f(hb));
            }
            *reinterpret_cast<s16x4*>(&sH[p][c0]) = hi.v;
            *reinterpret_cast<s16x4*>(&sL[p][c0]) = lo.v;
        }
        __syncthreads();
        short* xTo = xT   + ((size_t)pix0 << 6);
        short* xLo = xTlo + ((size_t)pix0 << 6);
#pragma unroll
        for (int r = 0; r < 4; ++r) {
            int u = (r << 8) + tid;
            int pp = u >> 3, ch8 = u & 7;
            *reinterpret_cast<bf16x8*>(xTo + pp * 64 + ch8 * 8) =
                *reinterpret_cast<const bf16x8*>(&sH[pp][ch8 * 8]);
            *reinterpret_cast<bf16x8*>(xLo + pp * 64 + ch8 * 8) =
                *reinterpret_cast<const bf16x8*>(&sL[pp][ch8 * 8]);
        }
    } else {
        int idx = (bid - 256) * 256 + tid;
        if (idx >= 55296) return;
        if (idx < 36864) {
            int e = idx & 7, o = (idx >> 3) & 63, h = (idx >> 9) & 3, s = idx >> 11;
            int k = s * 32 + h * 8 + e;
            int n = k >> 6, c = k & 63;
            wK[idx] = f2bf(w_conv[o * 576 + c * 9 + n]);
        } else {
            int j = idx - 36864;
            int e = j & 7, m = (j >> 3) & 31, h = (j >> 8) & 3, s = j >> 10;
            int k = s * 32 + h * 8 + e;
            int t = k >> 6, c = k & 63;
            float v = (m < 18) ? w_p[m * 576 + c * 9 + t] : 0.f;
            short hb = f2bf(v);
            wPh[j] = hb;
            wPl[j] = f2bf(v - bf2f(hb));
        }
    }
}

// ---------------- fused: 256 thr = 4 waves on 32 px; 4 blocks/CU ----------------
__global__ __launch_bounds__(256, 4) void k_fused(const short* __restrict__ xT,
                                                  const short* __restrict__ xTlo,
                                                  const short* __restrict__ wPh,
                                                  const short* __restrict__ wPl,
                                                  const short* __restrict__ wK,
                                                  const float* __restrict__ depth,
                                                  const float* __restrict__ b_p,
                                                  float* __restrict__ out) {
    // layout (bytes):
    //   win    [0,     23680)  x hi window: 185 px (5r x 37c) x 128B, XOR-swizzled
    //   dwin   [23680, 24420)  float[185]
    //   part1  [24448, 29568)  float[2][2][16][20]
    //   pw4    [29568, 34176)  float4[288]  (bilinear weights x m)
    //   pi4    [34176, 38784)  int4[288]    (corner indices; <0 => global fallback)
    //   accred overlays win [0, 10240): float[2*64][20] stride-20 (conflict-free)
    __shared__ __align__(16) char smem[38784];
    short* win    = (short*)smem;
    float* dwin   = (float*)(smem + 23680);
    float* part1  = (float*)(smem + 24448);
    float* pw4    = (float*)(smem + 29568);
    int*   pi4    = (int*)(smem + 34176);
    float* accred = (float*)smem;

    int tid = threadIdx.x;
    int lane = tid & 63;
    int wv = tid >> 6;                      // 0..3
    int l15 = lane & 15, h = lane >> 4;
    int ps = wv & 1;                        // pixel subtile (16 px)
    int kh = wv >> 1;                       // channel-half (ph1) / sample parity (ph2)
    int p0 = ps << 4;
    // XCD band swizzle (bijective: 1024 = 8*128)
    int bid = blockIdx.x;
    int swz = (bid & 7) * 128 + (bid >> 3);
    int pb = swz << 5;                      // 32-px tile
    int b = pb >> 14, i = (pb & 16383) >> 7, j0 = pb & 127;
    const short* xTb  = xT   + ((size_t)b << 20);
    const short* xTlb = xTlo + ((size_t)b << 20);
    const float* db = depth + (b << 14);

    // ---- stage: x hi window (5r x 37c) + depth window; coalesced ----
    for (int u = tid; u < 1480; u += 256) {
        int c8 = u & 7, px = u >> 3;
        int wr = px / 37, wc = px % 37;
        int r = i - 2 + wr, c = j0 - 2 + wc;
        bf16x8 v = {0, 0, 0, 0, 0, 0, 0, 0};
        if ((unsigned)r < 128u && (unsigned)c < 128u)
            v = *reinterpret_cast<const bf16x8*>(xTb + ((size_t)(r * 128 + c) << 6) + c8 * 8);
        *reinterpret_cast<bf16x8*>((char*)win + px * 128 + ((c8 ^ (px & 7)) << 4)) = v;
    }
    if (tid < 185) {
        int wr = tid / 37, wc = tid % 37;
        int r = i - 2 + wr, c = j0 - 2 + wc;
        dwin[tid] = ((unsigned)r < 128u && (unsigned)c < 128u) ? db[r * 128 + c] : 0.f;
    }
    __syncthreads();

    // ---- phase 1: offset conv; wave (ps,kh): 9 taps, channel half kh ----
    f32x4 acc0 = {0.f, 0.f, 0.f, 0.f}, acc1 = {0.f, 0.f, 0.f, 0.f};
    int c8p = kh * 4 + h;
#pragma unroll
    for (int t = 0; t < 9; ++t) {
        int s_ = t * 2 + kh;
        int wp = (t / 3 + 1) * 37 + (p0 + l15 + t % 3 + 1);
        bf16x8 bh = *reinterpret_cast<const bf16x8*>(
            (char*)win + wp * 128 + ((c8p ^ (wp & 7)) << 4));
        int si = i + t / 3 - 1;
        int sj = j0 + p0 + l15 + t % 3 - 1;
        bf16x8 bl = {0, 0, 0, 0, 0, 0, 0, 0};
        if ((unsigned)si < 128u && (unsigned)sj < 128u)
            bl = *reinterpret_cast<const bf16x8*>(
                xTlb + ((size_t)(si * 128 + sj) << 6) + c8p * 8);
        const short* wh_ = wPh + (size_t)((s_ * 4 + h) * 32 + l15) * 8;
        const short* wl_ = wPl + (size_t)((s_ * 4 + h) * 32 + l15) * 8;
        bf16x8 ah0 = *reinterpret_cast<const bf16x8*>(wh_);
        bf16x8 ah1 = *reinterpret_cast<const bf16x8*>(wh_ + 128);
        bf16x8 al0 = *reinterpret_cast<const bf16x8*>(wl_);
        bf16x8 al1 = *reinterpret_cast<const bf16x8*>(wl_ + 128);
        acc0 = MFMA16(ah0, bh, acc0);
        acc1 = MFMA16(ah1, bh, acc1);
        acc0 = MFMA16(ah0, bl, acc0);
        acc1 = MFMA16(ah1, bl, acc1);
        acc0 = MFMA16(al0, bh, acc0);
        acc1 = MFMA16(al1, bh, acc1);
    }
    {
        float* pp = part1 + ((ps * 2 + kh) * 16 + l15) * 20;
#pragma unroll
        for (int r = 0; r < 4; ++r) {
            pp[h * 4 + r] = acc0[r];
            int o1 = 16 + h * 4 + r;
            if (o1 < 18) pp[o1] = acc1[r];
        }
    }
    __syncthreads();

    // ---- epilogue: unit u = (p, n); offs inlined; depth bilinear -> pw4/pi4 ----
#pragma clang loop unroll(disable)
    for (int u = tid; u < 288; u += 256) {
        int p = u / 9, n = u % 9;
        int pps = p >> 4, pl = p & 15;
        const float* pa  = part1 + ((pps * 2) * 16 + pl) * 20;
        const float* pbm = part1 + ((pps * 2 + 1) * 16 + pl) * 20;
        float offx = pa[n] + pbm[n] + b_p[n];
        float offy = pa[9 + n] + pbm[9 + n] + b_p[9 + n];
        float gx = (float)(n / 3 - 1 + i + 1);
        float gy = (float)(n % 3 - 1 + j0 + p + 1);
        float dctr = dwin[2 * 37 + p + 2];
        float p1x = offx + gx, p1y = offy + gy;
        float fx = floorf(p1x), fy = floorf(p1y);
        float qltx = fminf(fmaxf(fx, 0.f), 127.f);
        float qlty = fminf(fmaxf(fy, 0.f), 127.f);
        float qrbx = fminf(fmaxf(fx + 1.f, 0.f), 127.f);
        float qrby = fminf(fmaxf(fy + 1.f, 0.f), 127.f);
        float pxc = fminf(fmaxf(p1x, 0.f), 127.f);
        float pyc = fminf(fmaxf(p1y, 0.f), 127.f);
        float glt = (1.f + (qltx - pxc)) * (1.f + (qlty - pyc));
        float grb = (1.f - (qrbx - pxc)) * (1.f - (qrby - pyc));
        float glb = (1.f + (qltx - pxc)) * (1.f - (qrby - pyc));
        float grt = (1.f - (qrbx - pxc)) * (1.f + (qlty - pyc));
        int ilx = (int)qltx, ily = (int)qlty, irx = (int)qrbx, iry = (int)qrby;
        auto dv = [&](int qx, int qy) -> float {
            if (qx < 1 || qx > 128 || qy < 1 || qy > 128) return 0.f;
            int r = qx - 1, c = qy - 1;
            int wr = r - (i - 2), wc = c - (j0 - 2);
            if ((unsigned)wr < 5u && (unsigned)wc < 37u) return dwin[wr * 37 + wc];
            return db[r * 128 + c];   // rare fallback
        };
        float dof = glt * dv(ilx, ily) + grb * dv(irx, iry) + glb * dv(ilx, iry) + grt * dv(irx, ily);
        float dd = fabsf(dctr - dof);
        float dwn = expf(-4.f * dd) + 0.25f;
        float mn = expf(-dd);
        float px = offx * dwn + gx;
        float py = offy * dwn + gy;
        float fx2 = floorf(px), fy2 = floorf(py);
        float xltx = fminf(fmaxf(fx2, 0.f), 129.f);
        float xlty = fminf(fmaxf(fy2, 0.f), 129.f);
        float xrbx = fminf(fmaxf(fx2 + 1.f, 0.f), 129.f);
        float xrby = fminf(fmaxf(fy2 + 1.f, 0.f), 129.f);
        float xpxc = fminf(fmaxf(px, 0.f), 129.f);
        float xpyc = fminf(fmaxf(py, 0.f), 129.f);
        float wlt = (1.f + (xltx - xpxc)) * (1.f + (xlty - xpyc));
        float wrb = (1.f - (xrbx - xpxc)) * (1.f - (xrby - xpyc));
        float wlb = (1.f + (xltx - xpxc)) * (1.f - (xrby - xpyc));
        float wrt = (1.f - (xrbx - xpxc)) * (1.f + (xlty - xpyc));
        int jlx = (int)xltx, jly = (int)xlty, jrx = (int)xrbx, jry = (int)xrby;
        float w4o[4];
        int i4o[4];
        auto mk = [&](int qx, int qy, float gw, int slot) {
            bool ok = (qx >= 1 && qx <= 128 && qy >= 1 && qy <= 128);
            w4o[slot] = ok ? gw * mn : 0.f;
            int idx = 0;   // weight 0 kills the (valid) window[0] read
            if (ok) {
                int r = qx - 1, c = qy - 1;
                int wr = r - (i - 2), wc = c - (j0 - 2);
                idx = ((unsigned)wr < 5u && (unsigned)wc < 37u) ? (wr * 37 + wc)
                                                                : (-1 - (r * 128 + c));
            }
            i4o[slot] = idx;
        };
        mk(jlx, jly, wlt, 0);
        mk(jrx, jry, wrb, 1);
        mk(jlx, jry, wlb, 2);
        mk(jrx, jly, wrt, 3);
        *reinterpret_cast<float4*>(pw4 + u * 4) = make_float4(w4o[0], w4o[1], w4o[2], w4o[3]);
        *reinterpret_cast<int4*>(pi4 + u * 4) = make_int4(i4o[0], i4o[1], i4o[2], i4o[3]);
    }

    // ---- prefetch first phase-2 iteration's wK frags (static addrs) ----
    const short* wkf0 = wK + (size_t)((kh * 8 + h) * 64 + l15) * 8;
    const short* wkf1 = wkf0 + 2048;
    bf16x8 f00 = *reinterpret_cast<const bf16x8*>(wkf0);
    bf16x8 f01 = *reinterpret_cast<const bf16x8*>(wkf0 + 128);
    bf16x8 f02 = *reinterpret_cast<const bf16x8*>(wkf0 + 256);
    bf16x8 f03 = *reinterpret_cast<const bf16x8*>(wkf0 + 384);
    bf16x8 f10 = *reinterpret_cast<const bf16x8*>(wkf1);
    bf16x8 f11 = *reinterpret_cast<const bf16x8*>(wkf1 + 128);
    bf16x8 f12 = *reinterpret_cast<const bf16x8*>(wkf1 + 256);
    bf16x8 f13 = *reinterpret_cast<const bf16x8*>(wkf1 + 384);
    __syncthreads();

    // ---- phase 2: raw-tap MFMA; wave (ps,kh): samples n%2==kh ----
    f32x4 A0 = {0.f, 0.f, 0.f, 0.f}, A1 = {0.f, 0.f, 0.f, 0.f};
    f32x4 A2 = {0.f, 0.f, 0.f, 0.f}, A3 = {0.f, 0.f, 0.f, 0.f};
    auto ph2_n = [&](int n, bf16x8 a00, bf16x8 a01, bf16x8 a02, bf16x8 a03,
                     bf16x8 a10, bf16x8 a11, bf16x8 a12, bf16x8 a13) {
        int uu = (p0 + l15) * 9 + n;
        float4 w4 = *reinterpret_cast<const float4*>(pw4 + uu * 4);
        int4 i4 = *reinterpret_cast<const int4*>(pi4 + uu * 4);
        const int* ip = &i4.x;
        const float* wp = &w4.x;
#pragma unroll
        for (int t = 0; t < 4; ++t) {
            int idx = ip[t];
            float w = wp[t];
            bf16x8 th0, th1;
            if (idx >= 0) {
                const char* base = (char*)win + idx * 128;
                th0 = *reinterpret_cast<const bf16x8*>(base + ((h ^ (idx & 7)) << 4));
                th1 = *reinterpret_cast<const bf16x8*>(base + (((4 + h) ^ (idx & 7)) << 4));
            } else {
                int gp = -1 - idx;   // rare global fallback
                const short* gb = xTb + ((size_t)gp << 6) + h * 8;
                th0 = *reinterpret_cast<const bf16x8*>(gb);
                th1 = *reinterpret_cast<const bf16x8*>(gb + 32);
            }
            f32x4 Z = {0.f, 0.f, 0.f, 0.f};
            f32x4 D0 = MFMA16(a00, th0, Z);
            f32x4 D1 = MFMA16(a01, th0, Z);
            f32x4 D2 = MFMA16(a02, th0, Z);
            f32x4 D3 = MFMA16(a03, th0, Z);
            D0 = MFMA16(a10, th1, D0);
            D1 = MFMA16(a11, th1, D1);
            D2 = MFMA16(a12, th1, D2);
            D3 = MFMA16(a13, th1, D3);
            A0 += w * D0;
            A1 += w * D1;
            A2 += w * D2;
            A3 += w * D3;
        }
    };
    ph2_n(kh, f00, f01, f02, f03, f10, f11, f12, f13);   // prefetched frags
#pragma clang loop unroll(disable)
    for (int n = kh + 2; n < 9; n += 2) {
        const short* wk0 = wK + (size_t)((n * 8 + h) * 64 + l15) * 8;
        const short* wk1 = wk0 + 2048;
        ph2_n(n,
              *reinterpret_cast<const bf16x8*>(wk0),
              *reinterpret_cast<const bf16x8*>(wk0 + 128),
              *reinterpret_cast<const bf16x8*>(wk0 + 256),
              *reinterpret_cast<const bf16x8*>(wk0 + 384),
              *reinterpret_cast<const bf16x8*>(wk1),
              *reinterpret_cast<const bf16x8*>(wk1 + 128),
              *reinterpret_cast<const bf16x8*>(wk1 + 256),
              *reinterpret_cast<const bf16x8*>(wk1 + 384));
    }
    __syncthreads();   // win dead -> accred overlay valid
    if (kh == 1) {
        float* ar = accred + (ps * 64 + lane) * 20;
        *reinterpret_cast<f32x4*>(ar)      = A0;
        *reinterpret_cast<f32x4*>(ar + 4)  = A1;
        *reinterpret_cast<f32x4*>(ar + 8)  = A2;
        *reinterpret_cast<f32x4*>(ar + 12) = A3;
    }
    __syncthreads();
    if (kh == 0) {
        const float* ar = accred + (ps * 64 + lane) * 20;
        int col = j0 + p0 + l15;
        size_t orow = ((size_t)b << 20) + ((size_t)i << 7) + col;   // o = 0 base
#pragma unroll
        for (int r = 0; r < 4; ++r) {
            out[orow + ((size_t)(h * 4 + r) << 14)]      = A0[r] + ar[r];
            out[orow + ((size_t)(16 + h * 4 + r) << 14)] = A1[r] + ar[4 + r];
            out[orow + ((size_t)(32 + h * 4 + r) << 14)] = A2[r] + ar[8 + r];
            out[orow + ((size_t)(48 + h * 4 + r) << 14)] = A3[r] + ar[12 + r];
        }
    }
}

extern "C" void kernel_launch(void* const* d_in, const int* in_sizes, int n_in,
                              void* d_out, int out_size, void* d_ws, size_t ws_size,
                              hipStream_t stream) {
    (void)in_sizes; (void)n_in; (void)out_size; (void)ws_size;
    const float* x      = (const float*)d_in[0];
    const float* depth  = (const float*)d_in[1];
    const float* w_p    = (const float*)d_in[2];
    const float* b_p    = (const float*)d_in[3];
    const float* w_conv = (const float*)d_in[4];
    float* out = (float*)d_out;

    char* wsb = (char*)d_ws;
    short* xT   = (short*)wsb;                     // 4,194,304 B
    short* xTlo = (short*)(wsb + 4194304);         // 4,194,304 B
    short* wK   = (short*)(wsb + 8388608);         //    73,728 B
    short* wPh  = (short*)(wsb + 8462336);         //    36,864 B
    short* wPl  = (short*)(wsb + 8499200);         //    36,864 B  (total ~8.54 MB)

    hipLaunchKernelGGL(k_prep,  dim3(472),  dim3(256), 0, stream,
                       x, w_conv, w_p, xT, xTlo, wK, wPh, wPl);
    hipLaunchKernelGGL(k_fused, dim3(1024), dim3(256), 0, stream,
                       xT, xTlo, wPh, wPl, wK, depth, b_p, out);
}